// Round 1
// baseline (620.322 us; speedup 1.0000x reference)
//
#include <hip/hip_runtime.h>
#include <math.h>

#define GRIDN    128
#define NRAYS    16384
#define STEPSZ   0.5f
#define MAXSTEPS 320
#define SEGS     16
#define SPS      (MAXSTEPS / SEGS)   // 20 steps per segment
#define RPB      32                  // rays per block
#define TPB      (RPB * SEGS)        // 512 threads

// One thread = one (ray, segment). Segments are stitched via the multiplicative
// transmittance decomposition: weight_k = exp(prefix_ll) * exp(local_ll) * (1-exp(att)).
// Depth-variance pass is fused via o_v = D2 - 2*E*D1 + E^2*A (identical weights in
// both reference passes).
__global__ __launch_bounds__(TPB, 4)
void march_kernel(const float* __restrict__ origins,
                  const float* __restrict__ dirs,
                  const int*   __restrict__ links,
                  const float* __restrict__ density,
                  const float* __restrict__ sh,
                  float* __restrict__ out)
{
    __shared__ float part[SEGS][RPB][8];  // rgb0,rgb1,rgb2, a, d1, d2, ll_sum, pad

    const int tid = threadIdx.x;
    const int r   = tid & (RPB - 1);
    const int seg = tid >> 5;             // RPB == 32
    const int ray = blockIdx.x * RPB + r;

    // ---- ray setup (faithful to reference math, fp32) ----
    const float owx = origins[ray * 3 + 0];
    const float owy = origins[ray * 3 + 1];
    const float owz = origins[ray * 3 + 2];
    const float dwx = dirs[ray * 3 + 0];
    const float dwy = dirs[ray * 3 + 1];
    const float dwz = dirs[ray * 3 + 2];

    const float invn = 1.0f / sqrtf(dwx * dwx + dwy * dwy + dwz * dwz);
    const float vx = dwx * invn, vy = dwy * invn, vz = dwz * invn;

    const float ox = 63.5f + owx * 64.0f;
    const float oy = 63.5f + owy * 64.0f;
    const float oz = 63.5f + owz * 64.0f;

    const float sxx = vx * 64.0f, syy = vy * 64.0f, szz = vz * 64.0f;
    const float ds  = 1.0f / sqrtf(sxx * sxx + syy * syy + szz * szz);  // delta_scale
    const float dx = sxx * ds, dy = syy * ds, dz = szz * ds;            // unit dirs

    // SH basis (degree 2, 9 coeffs), evaluated on the *unit world* direction
    float shm[9];
    shm[0] = 0.28209479177387814f;
    shm[1] = -0.4886025119029199f * vy;
    shm[2] =  0.4886025119029199f * vz;
    shm[3] = -0.4886025119029199f * vx;
    shm[4] =  1.0925484305920792f * vx * vy;
    shm[5] = -1.0925484305920792f * vy * vz;
    shm[6] =  0.31539156525252005f * (2.0f * vz * vz - vx * vx - vy * vy);
    shm[7] = -1.0925484305920792f * vx * vz;
    shm[8] =  0.5462742152960396f * (vx * vx - vy * vy);

    // ---- ray / box intersection ----
    float t0 = 0.0f;     // NEAR_CLIP
    float tmax = 1e9f;
    {
        const float o3[3] = { ox, oy, oz };
        const float d3[3] = { dx, dy, dz };
        #pragma unroll
        for (int a = 0; a < 3; a++) {
            if (d3[a] != 0.0f) {
                float inv = 1.0f / d3[a];
                float ta = (-0.5f  - o3[a]) * inv;
                float tb = (127.5f - o3[a]) * inv;
                t0   = fmaxf(t0,   fminf(ta, tb));
                tmax = fminf(tmax, fmaxf(ta, tb));
            }
        }
    }

    // ---- march this segment ----
    float ll = 0.0f;                       // local log-light
    float aR = 0.0f, aG = 0.0f, aB = 0.0f; // weighted rgb
    float aA = 0.0f;                       // sum of weights
    float aD1 = 0.0f, aD2 = 0.0f;          // sum w*d, sum w*d^2

    int cached_cell = -1;
    float csig[8], cr0[8], cr1[8], cr2[8]; // per-corner density + SH-contracted rgb

    const int k0 = seg * SPS;
    for (int i = 0; i < SPS; i++) {
        const float t = t0 + (float)(k0 + i) * STEPSZ;
        if (t > tmax) break;   // exact: inactive steps contribute nothing and t grows

        float px = fminf(fmaxf(ox + t * dx, 0.0f), 127.0f);
        float py = fminf(fmaxf(oy + t * dy, 0.0f), 127.0f);
        float pz = fminf(fmaxf(oz + t * dz, 0.0f), 127.0f);
        const int lx = min(max((int)px, 0), 126);
        const int ly = min(max((int)py, 0), 126);
        const int lz = min(max((int)pz, 0), 126);
        const float fx = px - (float)lx;
        const float fy = py - (float)ly;
        const float fz = pz - (float)lz;

        const int cell = (lx << 14) | (ly << 7) | lz;  // == (lx*128+ly)*128+lz
        if (cell != cached_cell) {
            cached_cell = cell;
            #pragma unroll
            for (int c = 0; c < 8; c++) {
                const int cdx = (c >> 2) & 1, cdy = (c >> 1) & 1, cdz = c & 1;
                const int idx = cell + (cdx << 14) + (cdy << 7) + cdz;
                const int lnk = links[idx];
                float s = 0.0f, q0 = 0.0f, q1 = 0.0f, q2 = 0.0f;
                if (lnk >= 0) {
                    s = density[lnk];
                    const float* row = sh + (long long)lnk * 27;
                    #pragma unroll
                    for (int k = 0; k < 9; k++) {
                        const float m = shm[k];
                        q0 += m * row[k];
                        q1 += m * row[9 + k];
                        q2 += m * row[18 + k];
                    }
                }
                csig[c] = s; cr0[c] = q0; cr1[c] = q1; cr2[c] = q2;
            }
        }

        // trilinear weights, corner order c = dx*4 + dy*2 + dz
        const float gx1 = fx, gx0 = 1.0f - fx;
        const float gy1 = fy, gy0 = 1.0f - fy;
        const float gz1 = fz, gz0 = 1.0f - fz;
        float w[8];
        w[0] = gx0 * gy0 * gz0; w[1] = gx0 * gy0 * gz1;
        w[2] = gx0 * gy1 * gz0; w[3] = gx0 * gy1 * gz1;
        w[4] = gx1 * gy0 * gz0; w[5] = gx1 * gy0 * gz1;
        w[6] = gx1 * gy1 * gz0; w[7] = gx1 * gy1 * gz1;

        float sigma = 0.0f, c0 = 0.0f, c1 = 0.0f, c2 = 0.0f;
        #pragma unroll
        for (int c = 0; c < 8; c++) {
            sigma += w[c] * csig[c];
            c0    += w[c] * cr0[c];
            c1    += w[c] * cr1[c];
            c2    += w[c] * cr2[c];
        }

        const float la = -STEPSZ * fmaxf(sigma, 0.0f) * ds;   // log attenuation
        const float ws = expf(ll) * (1.0f - expf(la));        // local weight
        c0 = fmaxf(c0 + 0.5f, 0.0f);
        c1 = fmaxf(c1 + 0.5f, 0.0f);
        c2 = fmaxf(c2 + 0.5f, 0.0f);

        aR += ws * c0; aG += ws * c1; aB += ws * c2;
        aA += ws;
        const float dd = t * ds;
        aD1 += ws * dd;
        aD2 += ws * dd * dd;
        ll  += la;
    }

    part[seg][r][0] = aR;  part[seg][r][1] = aG;  part[seg][r][2] = aB;
    part[seg][r][3] = aA;  part[seg][r][4] = aD1; part[seg][r][5] = aD2;
    part[seg][r][6] = ll;
    __syncthreads();

    // ---- stitch segments (one thread per ray) ----
    if (tid < RPB) {
        float pre = 0.0f;
        float R = 0.0f, G = 0.0f, Bc = 0.0f, A = 0.0f, D1 = 0.0f, D2 = 0.0f;
        for (int s = 0; s < SEGS; s++) {
            const float T = expf(pre);
            R  += T * part[s][tid][0];
            G  += T * part[s][tid][1];
            Bc += T * part[s][tid][2];
            A  += T * part[s][tid][3];
            D1 += T * part[s][tid][4];
            D2 += T * part[s][tid][5];
            pre += part[s][tid][6];
        }
        const float bg    = expf(pre);        // * BG (=1)
        const float denom = fmaxf(A, 1e-10f);
        const float E     = D1 / denom;       // depth (same as reference pass 1)
        const float ov    = D2 - 2.0f * E * D1 + E * E * A;

        const int o = (blockIdx.x * RPB + tid) * 6;
        out[o + 0] = R  + bg;
        out[o + 1] = G  + bg;
        out[o + 2] = Bc + bg;
        out[o + 3] = A;
        out[o + 4] = E;
        out[o + 5] = ov / denom;
    }
}

extern "C" void kernel_launch(void* const* d_in, const int* in_sizes, int n_in,
                              void* d_out, int out_size, void* d_ws, size_t ws_size,
                              hipStream_t stream) {
    const float* origins = (const float*)d_in[0];
    const float* dirs    = (const float*)d_in[1];
    const int*   links   = (const int*)d_in[2];
    const float* density = (const float*)d_in[3];
    const float* sh      = (const float*)d_in[4];
    float* out = (float*)d_out;

    dim3 grid(NRAYS / RPB);   // 512 blocks
    dim3 block(TPB);          // 512 threads = 32 rays x 16 segments
    march_kernel<<<grid, block, 0, stream>>>(origins, dirs, links, density, sh, out);
}